// Round 11
// baseline (1186.078 us; speedup 1.0000x reference)
//
#include <hip/hip_runtime.h>

#define NB 256
#define NT 1000
#define ND 64
#define NH 128

typedef _Float16 h2 __attribute__((ext_vector_type(2)));
typedef _Float16 f16x8 __attribute__((ext_vector_type(8)));
typedef float    f32x4 __attribute__((ext_vector_type(4)));
typedef uint     u32x4 __attribute__((ext_vector_type(4)));

static __device__ __forceinline__ uint pk(float a, float b) {
    return __builtin_bit_cast(uint, __builtin_amdgcn_cvt_pkrtz(a, b));
}
static __device__ __forceinline__ float fdot2u(uint a, uint b, float c) {
#if __has_builtin(__builtin_amdgcn_fdot2)
    return __builtin_amdgcn_fdot2(__builtin_bit_cast(h2, a),
                                  __builtin_bit_cast(h2, b), c, false);
#else
    h2 ha = __builtin_bit_cast(h2, a), hb = __builtin_bit_cast(h2, b);
    return c + (float)ha.x * (float)hb.x + (float)ha.y * (float)hb.y;
#endif
}
static __device__ __forceinline__ float f16lo(uint u) {
    return (float)__builtin_bit_cast(h2, u).x;
}
static __device__ __forceinline__ float f16hi(uint u) {
    return (float)__builtin_bit_cast(h2, u).y;
}
static __device__ __forceinline__ float sigmoid_f(float x) {
    float e = __builtin_amdgcn_exp2f(-1.4426950408889634f * x);
    return __builtin_amdgcn_rcpf(1.0f + e);
}
static __device__ __forceinline__ float tanh_f(float x) {
    float e = __builtin_amdgcn_exp2f(-2.8853900817779268f * x);
    return 2.0f * __builtin_amdgcn_rcpf(1.0f + e) - 1.0f;
}
// quad butterfly sum via DPP
static __device__ __forceinline__ float qsum(float v) {
    int a = __builtin_amdgcn_update_dpp(0, __builtin_bit_cast(int, v),
                                        0xB1, 0xF, 0xF, true);
    v += __builtin_bit_cast(float, a);
    int b = __builtin_amdgcn_update_dpp(0, __builtin_bit_cast(int, v),
                                        0x4E, 0xF, 0xF, true);
    v += __builtin_bit_cast(float, b);
    return v;
}
// load 8 consecutive f32, pack to 4 f16x2 regs
static __device__ __forceinline__ void ld8(const float* p, uint* d) {
    const float4 A = *(const float4*)p;
    const float4 B = *(const float4*)(p + 4);
    d[0] = pk(A.x, A.y); d[1] = pk(A.z, A.w);
    d[2] = pk(B.x, B.y); d[3] = pk(B.z, B.w);
}
// load 8 consecutive f32 as one MFMA A-fragment (layout verified in round 6)
static __device__ __forceinline__ f16x8 ldWfrag(const float* p) {
    const float4 a = *(const float4*)p;
    const float4 b = *(const float4*)(p + 4);
    u32x4 u = { pk(a.x, a.y), pk(a.z, a.w), pk(b.x, b.y), pk(b.z, b.w) };
    return __builtin_bit_cast(f16x8, u);
}
static __device__ __forceinline__ float gi_e(uint2 g, int rr) {
    const uint wd = (rr < 2) ? g.x : g.y;
    return (rr & 1) ? f16hi(wd) : f16lo(wd);
}
#define PIN(v) asm volatile("" : "+v"(v))
#define MFMA(a, b, c) __builtin_amdgcn_mfma_f32_16x16x32_f16((a), (b), (c), 0, 0, 0)
// raw barrier: orders LDS only; global prefetch loads stay in flight
#define WAVEBAR() asm volatile("s_waitcnt lgkmcnt(0)\n\ts_barrier" ::: "memory")

// ---------- M = W_hh (384x128) @ nW2 (128x128), f32 ----------
__global__ __launch_bounds__(128) void mfuse(
    const float* __restrict__ W_hh, const float* __restrict__ nW2,
    float* __restrict__ M)
{
    __shared__ float wrow[NH];
    const int r = blockIdx.x;
    const int j = threadIdx.x;
    wrow[j] = W_hh[(size_t)r * NH + j];
    __syncthreads();
    float a0 = 0.0f, a1 = 0.0f, a2 = 0.0f, a3 = 0.0f;
#pragma unroll 8
    for (int k = 0; k < NH; k += 4) {
        a0 += wrow[k]     * nW2[(size_t)(k)     * NH + j];
        a1 += wrow[k + 1] * nW2[(size_t)(k + 1) * NH + j];
        a2 += wrow[k + 2] * nW2[(size_t)(k + 2) * NH + j];
        a3 += wrow[k + 3] * nW2[(size_t)(k + 3) * NH + j];
    }
    M[(size_t)r * NH + j] = (a0 + a1) + (a2 + a3);
}

// ---------- cv[r] = dot(W_hh[r], node_b2) ----------
__global__ __launch_bounds__(128) void cvk(
    const float* __restrict__ W_hh, const float* __restrict__ nb2,
    float* __restrict__ cv)
{
    const int r = blockIdx.x * 128 + threadIdx.x;   // 0..383
    const float* wr = W_hh + (size_t)r * NH;
    float a = 0.0f;
#pragma unroll 8
    for (int k = 0; k < NH; ++k) a += wr[k] * nb2[k];
    cv[r] = a;
}

// ---------- gi precompute: giu[t][b][row] (f16), row = g*128+j ----------
__global__ __launch_bounds__(384) void gi_pre(
    const float* __restrict__ x,      // (B,T,D)
    const float* __restrict__ W_ih,   // (384,64)
    ushort* __restrict__ giu)         // (T,B,384)
{
    __shared__ uint xt[125][32];
    const int tid = threadIdx.x;
    const int b   = blockIdx.x;
    const int t0  = blockIdx.y * 125;

    uint wr[32];
    const float* wrow = W_ih + (size_t)tid * ND;
#pragma unroll
    for (int k = 0; k < 8; ++k) ld8(wrow + k * 8, wr + k * 4);

    for (int i = tid; i < 125 * 32; i += 384) {
        const int t = i >> 5, c = i & 31;
        const float2 v = *(const float2*)(x + ((size_t)b * NT + t0 + t) * ND + c * 2);
        xt[t][c] = pk(v.x, v.y);
    }
    __syncthreads();

    for (int t = 0; t < 125; ++t) {
        const uint4* xr = (const uint4*)&xt[t][0];
        float a0 = 0.0f, a1 = 0.0f;
#pragma unroll
        for (int k4 = 0; k4 < 8; ++k4) {
            const uint4 hv = xr[k4];
            a0 = fdot2u(wr[k4 * 4 + 0], hv.x, a0);
            a1 = fdot2u(wr[k4 * 4 + 1], hv.y, a1);
            a0 = fdot2u(wr[k4 * 4 + 2], hv.z, a0);
            a1 = fdot2u(wr[k4 * 4 + 3], hv.w, a1);
        }
        giu[((size_t)(t0 + t) * NB + b) * 384 + tid] =
            __builtin_bit_cast(ushort, (_Float16)(a0 + a1));
    }
}

// ---------- MFMA 2-phase scan: one block per batch row, B-operand broadcast ----------
__global__
__attribute__((amdgpu_flat_work_group_size(512, 512)))
__attribute__((amdgpu_waves_per_eu(2, 2)))
void gruode_scan_mfma(
    const float* __restrict__ tps,
    const int*   __restrict__ mask,
    const float* __restrict__ W_hh,
    const float* __restrict__ b_ih,
    const float* __restrict__ b_hh,
    const float* __restrict__ nW1,
    const float* __restrict__ nb1,
    const float* __restrict__ nW2,
    const float* __restrict__ nb2,
    const float* __restrict__ W_out,
    const float* __restrict__ b_out,
    const float* __restrict__ Mw,     // (384,128) = W_hh @ nW2
    const float* __restrict__ cv,     // (384)     = W_hh @ nb2
    const ushort* __restrict__ giu,   // (T,B,384) f16
    float* __restrict__ out)          // (B,128)
{
    __shared__ __align__(16) _Float16 sh_h[2][NH];
    __shared__ __align__(16) _Float16 sh_tmp[NH];
    __shared__ float sh_dt[NT];
    __shared__ int   sh_m[NT];

    const int tid  = threadIdx.x;
    const int w    = tid >> 6;        // wave 0..7 owns rows w*16..+15 of each set
    const int lane = tid & 63;
    const int n    = lane & 15;       // A row-within-tile / D col (cols replicated)
    const int kg   = lane >> 4;       // k-group; D rows kg*4+rr
    const int b    = blockIdx.x;
    const int jb   = w * 16 + kg * 4; // this lane's first j

    // ---- A-fragments (round-6-verified layout). Spills land in AGPR = free for MFMA.
    f16x8 w1F[4], whrF[4], whzF[4], whnF[4];
    f16x8 w2F[4], mrF[4], mzF[4], mnF[4];
#pragma unroll
    for (int ks = 0; ks < 4; ++ks) {
        const int c   = ks * 32 + kg * 8;
        const int row = w * 16 + n;
        w1F[ks]  = ldWfrag(nW1  + (size_t)row         * NH + c);
        whrF[ks] = ldWfrag(W_hh + (size_t)row         * NH + c);
        whzF[ks] = ldWfrag(W_hh + (size_t)(row + 128) * NH + c);
        whnF[ks] = ldWfrag(W_hh + (size_t)(row + 256) * NH + c);
        w2F[ks]  = ldWfrag(nW2  + (size_t)row         * NH + c);
        mrF[ks]  = ldWfrag(Mw   + (size_t)row         * NH + c);
        mzF[ks]  = ldWfrag(Mw   + (size_t)(row + 128) * NH + c);
        mnF[ks]  = ldWfrag(Mw   + (size_t)(row + 256) * NH + c);
    }
#pragma unroll
    for (int ks = 0; ks < 4; ++ks) {
        PIN(w1F[ks]); PIN(whrF[ks]); PIN(whzF[ks]); PIN(whnF[ks]);
        PIN(w2F[ks]); PIN(mrF[ks]);  PIN(mzF[ks]);  PIN(mnF[ks]);
    }
    // ---- per-rr scalars (j = jb + rr)
    float bb1v[4], bb2v[4], brzr[4], brzz[4], binn[4], bhnn[4];
    float crv[4], czv[4], cnv[4];
#pragma unroll
    for (int rr = 0; rr < 4; ++rr) {
        const int j = jb + rr;
        bb1v[rr] = nb1[j];
        bb2v[rr] = nb2[j];
        brzr[rr] = b_ih[j] + b_hh[j];
        brzz[rr] = b_ih[j + 128] + b_hh[j + 128];
        binn[rr] = b_ih[j + 256];
        bhnn[rr] = b_hh[j + 256];
        crv[rr]  = cv[j];
        czv[rr]  = cv[j + 128];
        cnv[rr]  = cv[j + 256];
    }

    // ---- stage dt / mask; init h
    for (int s = tid; s < NT; s += 512) {
        sh_dt[s] = (s == 0) ? 0.0f : (tps[s] - tps[s - 1]);
        sh_m[s]  = mask[b * NT + s];
    }
    if (tid < NH) sh_h[0][tid] = (_Float16)0.0f;
    __syncthreads();

    // ---- gi prefetch (2 deep; stays in flight across WAVEBAR)
    const size_t GSTR = (size_t)NB * 384;
    const ushort* gb = giu + (size_t)b * 384 + jb;
    uint2 grc = *(const uint2*)(gb);
    uint2 gzc = *(const uint2*)(gb + 128);
    uint2 gnc = *(const uint2*)(gb + 256);
    uint2 grn = *(const uint2*)(gb + GSTR);
    uint2 gzn = *(const uint2*)(gb + GSTR + 128);
    uint2 gnn = *(const uint2*)(gb + GSTR + 256);

    float hj[4] = {0, 0, 0, 0}, hlast[4] = {0, 0, 0, 0};
    int   seen = 0;
    float dtc = sh_dt[0];
    int   mc  = sh_m[0];
    const f32x4 z4 = {0, 0, 0, 0};

    for (int s = 0; s < NT; ++s) {
        const int cur = s & 1, nxt = cur ^ 1;
        const int m   = mc;                     // uniform per block
        const float dte = seen ? dtc : 0.0f;    // r_fill freeze

        // prefetch step s+2
        const int sp = (s + 2 < NT) ? (s + 2) : (NT - 1);
        const ushort* g2 = gb + (size_t)sp * GSTR;
        const uint2 grp = *(const uint2*)(g2);
        const uint2 gzp = *(const uint2*)(g2 + 128);
        const uint2 gnp = *(const uint2*)(g2 + 256);
        const int sn = (s + 1 < NT) ? (s + 1) : s;
        const float dt_n = sh_dt[sn];
        const int   m_n  = sh_m[sn];

        // ---- phase A: broadcast-B MFMA of [W1 | Whh_r | Whh_z | Whh_n] @ h
        const char* hb = (const char*)&sh_h[cur][0];
        const f16x8 bh0 = *(const f16x8*)(hb +       kg * 16);
        const f16x8 bh1 = *(const f16x8*)(hb +  64 + kg * 16);
        const f16x8 bh2 = *(const f16x8*)(hb + 128 + kg * 16);
        const f16x8 bh3 = *(const f16x8*)(hb + 192 + kg * 16);
        f32x4 D1 = MFMA(w1F[0], bh0, z4);
        D1 = MFMA(w1F[1], bh1, D1);
        D1 = MFMA(w1F[2], bh2, D1);
        D1 = MFMA(w1F[3], bh3, D1);
        f32x4 Dr = z4, Dz = z4, Dn = z4;
        if (m) {
            Dr = MFMA(whrF[0], bh0, z4); Dr = MFMA(whrF[1], bh1, Dr);
            Dr = MFMA(whrF[2], bh2, Dr); Dr = MFMA(whrF[3], bh3, Dr);
            Dz = MFMA(whzF[0], bh0, z4); Dz = MFMA(whzF[1], bh1, Dz);
            Dz = MFMA(whzF[2], bh2, Dz); Dz = MFMA(whzF[3], bh3, Dz);
            Dn = MFMA(whnF[0], bh0, z4); Dn = MFMA(whnF[1], bh1, Dn);
            Dn = MFMA(whnF[2], bh2, Dn); Dn = MFMA(whnF[3], bh3, Dn);
        }
        const float t0 = tanh_f(D1[0] + bb1v[0]);
        const float t1 = tanh_f(D1[1] + bb1v[1]);
        const float t2 = tanh_f(D1[2] + bb1v[2]);
        const float t3 = tanh_f(D1[3] + bb1v[3]);
        if (n == 0)
            *(uint2*)((char*)sh_tmp + w * 32 + kg * 8) =
                make_uint2(pk(t0, t1), pk(t2, t3));
        WAVEBAR();

        // ---- phase B: [W2 | M_r | M_z | M_n] @ tmp ; gates
        const char* tb = (const char*)sh_tmp;
        const f16x8 bt0 = *(const f16x8*)(tb +       kg * 16);
        const f16x8 bt1 = *(const f16x8*)(tb +  64 + kg * 16);
        const f16x8 bt2 = *(const f16x8*)(tb + 128 + kg * 16);
        const f16x8 bt3 = *(const f16x8*)(tb + 192 + kg * 16);
        f32x4 D2 = MFMA(w2F[0], bt0, z4);
        D2 = MFMA(w2F[1], bt1, D2);
        D2 = MFMA(w2F[2], bt2, D2);
        D2 = MFMA(w2F[3], bt3, D2);
        float hnew[4];
        if (m) {
            f32x4 Mr = MFMA(mrF[0], bt0, z4);
            Mr = MFMA(mrF[1], bt1, Mr); Mr = MFMA(mrF[2], bt2, Mr); Mr = MFMA(mrF[3], bt3, Mr);
            f32x4 Mz = MFMA(mzF[0], bt0, z4);
            Mz = MFMA(mzF[1], bt1, Mz); Mz = MFMA(mzF[2], bt2, Mz); Mz = MFMA(mzF[3], bt3, Mz);
            f32x4 Mn = MFMA(mnF[0], bt0, z4);
            Mn = MFMA(mnF[1], bt1, Mn); Mn = MFMA(mnF[2], bt2, Mn); Mn = MFMA(mnF[3], bt3, Mn);
#pragma unroll
            for (int rr = 0; rr < 4; ++rr) {
                const float hode = hj[rr] + dte * (D2[rr] + bb2v[rr]);
                const float sr = Dr[rr] + dte * (Mr[rr] + crv[rr]) + gi_e(grc, rr) + brzr[rr];
                const float sz = Dz[rr] + dte * (Mz[rr] + czv[rr]) + gi_e(gzc, rr) + brzz[rr];
                const float hn = Dn[rr] + dte * (Mn[rr] + cnv[rr]) + bhnn[rr];
                const float r  = sigmoid_f(sr);
                const float z  = sigmoid_f(sz);
                const float nn = tanh_f(gi_e(gnc, rr) + binn[rr] + r * hn);
                hnew[rr]  = (1.0f - z) * nn + z * hode;
                hlast[rr] = hnew[rr];
            }
        } else {
#pragma unroll
            for (int rr = 0; rr < 4; ++rr)
                hnew[rr] = hj[rr] + dte * (D2[rr] + bb2v[rr]);
        }
#pragma unroll
        for (int rr = 0; rr < 4; ++rr) hj[rr] = hnew[rr];
        if (n == 0)
            *(uint2*)((char*)&sh_h[nxt][0] + w * 32 + kg * 8) =
                make_uint2(pk(hnew[0], hnew[1]), pk(hnew[2], hnew[3]));
        seen |= m;
        grc = grn; gzc = gzn; gnc = gnn;
        grn = grp; gzn = gzp; gnn = gnp;
        dtc = dt_n; mc = m_n;
        WAVEBAR();
    }

    // ---- epilogue: out = W_out @ h_last + b_out (MFMA, broadcast B)
    if (n == 0)
        *(uint2*)((char*)sh_tmp + w * 32 + kg * 8) =
            make_uint2(pk(hlast[0], hlast[1]), pk(hlast[2], hlast[3]));
    __syncthreads();
    const char* eb = (const char*)sh_tmp;
    const f16x8 be0 = *(const f16x8*)(eb +       kg * 16);
    const f16x8 be1 = *(const f16x8*)(eb +  64 + kg * 16);
    const f16x8 be2 = *(const f16x8*)(eb + 128 + kg * 16);
    const f16x8 be3 = *(const f16x8*)(eb + 192 + kg * 16);
    f32x4 Do = z4;
    Do = MFMA(ldWfrag(W_out + (size_t)(w * 16 + n) * NH +  0 + kg * 8), be0, Do);
    Do = MFMA(ldWfrag(W_out + (size_t)(w * 16 + n) * NH + 32 + kg * 8), be1, Do);
    Do = MFMA(ldWfrag(W_out + (size_t)(w * 16 + n) * NH + 64 + kg * 8), be2, Do);
    Do = MFMA(ldWfrag(W_out + (size_t)(w * 16 + n) * NH + 96 + kg * 8), be3, Do);
    if (n == 0) {
        float4 o;
        o.x = Do[0] + b_out[jb];
        o.y = Do[1] + b_out[jb + 1];
        o.z = Do[2] + b_out[jb + 2];
        o.w = Do[3] + b_out[jb + 3];
        *(float4*)(out + (size_t)b * NH + jb) = o;
    }
}

// ---------- fallback VALU scan (round-10, GI=0 path) ----------
__global__
__attribute__((amdgpu_flat_work_group_size(512, 512)))
__attribute__((amdgpu_waves_per_eu(2, 2)))
void gruode_scan_valu(
    const float* __restrict__ x,
    const float* __restrict__ tps,
    const int*   __restrict__ mask,
    const float* __restrict__ W_ih,
    const float* __restrict__ W_hh,
    const float* __restrict__ b_ih,
    const float* __restrict__ b_hh,
    const float* __restrict__ nW1,
    const float* __restrict__ nb1,
    const float* __restrict__ nW2,
    const float* __restrict__ nb2,
    const float* __restrict__ W_out,
    const float* __restrict__ b_out,
    const float* __restrict__ Mw,
    float* __restrict__ out)
{
    __shared__ __align__(16) _Float16 sh_h[2][NH];
    __shared__ __align__(16) _Float16 sh_tmp[NH];
    __shared__ float sh_eo[NH];
    __shared__ float sh_dt[NT];
    __shared__ int   sh_m[NT];

    const int tid = threadIdx.x;
    const int j   = tid >> 2;
    const int q   = tid & 3;
    const int b   = blockIdx.x;
    const int kb  = q * 32;
    const int qb  = q * 64;

#define WSEL(i) (((i) + (q >> 1)) & 3)

    uint w1[4][4], w2[4][4], whr[4][4], whz[4][4], whn[4][4];
    uint mr[4][4], mz[4][4], mn[4][4];
#pragma unroll
    for (int i = 0; i < 4; ++i) {
        const int c = kb + (WSEL(i) << 3);
        ld8(nW1  + (size_t)(j      ) * NH + c, w1[i]);
        ld8(nW2  + (size_t)(j      ) * NH + c, w2[i]);
        ld8(W_hh + (size_t)(j      ) * NH + c, whr[i]);
        ld8(W_hh + (size_t)(j + 128) * NH + c, whz[i]);
        ld8(W_hh + (size_t)(j + 256) * NH + c, whn[i]);
        ld8(Mw   + (size_t)(j      ) * NH + c, mr[i]);
        ld8(Mw   + (size_t)(j + 128) * NH + c, mz[i]);
        ld8(Mw   + (size_t)(j + 256) * NH + c, mn[i]);
    }
    uint wir[8], wiz[8], win[8];
    {
        const int kbi = q * 16;
        ld8(W_ih + (size_t)(j      ) * ND + kbi,     wir);
        ld8(W_ih + (size_t)(j      ) * ND + kbi + 8, wir + 4);
        ld8(W_ih + (size_t)(j + 128) * ND + kbi,     wiz);
        ld8(W_ih + (size_t)(j + 128) * ND + kbi + 8, wiz + 4);
        ld8(W_ih + (size_t)(j + 256) * ND + kbi,     win);
        ld8(W_ih + (size_t)(j + 256) * ND + kbi + 8, win + 4);
    }
    float bb1   = nb1[j];
    float bb2   = nb2[j];
    float brz_r = b_ih[j]       + b_hh[j];
    float brz_z = b_ih[j + 128] + b_hh[j + 128];
    float bin_n = b_ih[j + 256];
    float bhn_n = b_hh[j + 256];

    float cr = 0.0f, cz = 0.0f, cn = 0.0f;
    {
        uint b2p[4];
#pragma unroll
        for (int i = 0; i < 4; ++i) {
            const int c = kb + (WSEL(i) << 3);
            ld8(nb2 + c, b2p);
#pragma unroll
            for (int k = 0; k < 4; ++k) {
                cr = fdot2u(whr[i][k], b2p[k], cr);
                cz = fdot2u(whz[i][k], b2p[k], cz);
                cn = fdot2u(whn[i][k], b2p[k], cn);
            }
        }
        cr = qsum(cr); cz = qsum(cz); cn = qsum(cn);
    }

    for (int s = tid; s < NT; s += 512) {
        sh_dt[s] = (s == 0) ? 0.0f : (tps[s] - tps[s - 1]);
        sh_m[s]  = mask[b * NT + s];
    }
    if (tid < NH) sh_h[0][tid] = (_Float16)0.0f;
    __syncthreads();

    float hj = 0.0f, hlast = 0.0f;
    int   seen = 0;

    const float* xbase = x + (size_t)b * NT * ND + q * 16;
    float4 xc0 = *(const float4*)(xbase);
    float4 xc1 = *(const float4*)(xbase + 4);
    float4 xc2 = *(const float4*)(xbase + 8);
    float4 xc3 = *(const float4*)(xbase + 12);
    float dtc = sh_dt[0];
    int   mc  = sh_m[0];

    for (int s = 0; s < NT; ++s) {
        const int cur = s & 1, nxt = cur ^ 1;
        const int sn_ = (s + 1 < NT) ? (s + 1) : s;
        const float* xr = xbase + (size_t)sn_ * ND;
        const float4 xn0 = *(const float4*)(xr);
        const float4 xn1 = *(const float4*)(xr + 4);
        const float4 xn2 = *(const float4*)(xr + 8);
        const float4 xn3 = *(const float4*)(xr + 12);
        const float dt_n = sh_dt[sn_];
        const int   m_n  = sh_m[sn_];

        const int   m   = mc;
        const float dte = seen ? dtc : 0.0f;

        uint xh[8];
        xh[0] = pk(xc0.x, xc0.y); xh[1] = pk(xc0.z, xc0.w);
        xh[2] = pk(xc1.x, xc1.y); xh[3] = pk(xc1.z, xc1.w);
        xh[4] = pk(xc2.x, xc2.y); xh[5] = pk(xc2.z, xc2.w);
        xh[6] = pk(xc3.x, xc3.y); xh[7] = pk(xc3.z, xc3.w);
        float grf = 0.0f, gzf = 0.0f, gnf = 0.0f;
#pragma unroll
        for (int k = 0; k < 8; ++k) {
            grf = fdot2u(wir[k], xh[k], grf);
            gzf = fdot2u(wiz[k], xh[k], gzf);
            gnf = fdot2u(win[k], xh[k], gnf);
        }

        float a1 = 0.0f, ahr = 0.0f, ahz = 0.0f, ahn = 0.0f;
        const char* hb = (const char*)&sh_h[cur][0];
#pragma unroll
        for (int i = 0; i < 4; ++i) {
            const uint4 hv = *(const uint4*)(hb + qb + WSEL(i) * 16);
            a1  = fdot2u(w1[i][0],  hv.x, a1);  a1  = fdot2u(w1[i][1],  hv.y, a1);
            a1  = fdot2u(w1[i][2],  hv.z, a1);  a1  = fdot2u(w1[i][3],  hv.w, a1);
            ahr = fdot2u(whr[i][0], hv.x, ahr); ahr = fdot2u(whr[i][1], hv.y, ahr);
            ahr = fdot2u(whr[i][2], hv.z, ahr); ahr = fdot2u(whr[i][3], hv.w, ahr);
            ahz = fdot2u(whz[i][0], hv.x, ahz); ahz = fdot2u(whz[i][1], hv.y, ahz);
            ahz = fdot2u(whz[i][2], hv.z, ahz); ahz = fdot2u(whz[i][3], hv.w, ahz);
            ahn = fdot2u(whn[i][0], hv.x, ahn); ahn = fdot2u(whn[i][1], hv.y, ahn);
            ahn = fdot2u(whn[i][2], hv.z, ahn); ahn = fdot2u(whn[i][3], hv.w, ahn);
        }
        const float a1q = qsum(a1);
        if (q == 0) sh_tmp[j] = (_Float16)tanh_f(a1q + bb1);
        WAVEBAR();

        float a2 = 0.0f, amr = 0.0f, amz = 0.0f, amn = 0.0f;
#pragma unroll
        for (int i = 0; i < 4; ++i) {
            const uint4 tv = *(const uint4*)((const char*)sh_tmp + qb + WSEL(i) * 16);
            a2  = fdot2u(w2[i][0], tv.x, a2);  a2  = fdot2u(w2[i][1], tv.y, a2);
            a2  = fdot2u(w2[i][2], tv.z, a2);  a2  = fdot2u(w2[i][3], tv.w, a2);
            amr = fdot2u(mr[i][0], tv.x, amr); amr = fdot2u(mr[i][1], tv.y, amr);
            amr = fdot2u(mr[i][2], tv.z, amr); amr = fdot2u(mr[i][3], tv.w, amr);
            amz = fdot2u(mz[i][0], tv.x, amz); amz = fdot2u(mz[i][1], tv.y, amz);
            amz = fdot2u(mz[i][2], tv.z, amz); amz = fdot2u(mz[i][3], tv.w, amz);
            amn = fdot2u(mn[i][0], tv.x, amn); amn = fdot2u(mn[i][1], tv.y, amn);
            amn = fdot2u(mn[i][2], tv.z, amn); amn = fdot2u(mn[i][3], tv.w, amn);
        }
        const float a2q  = qsum(a2);
        const float hode = hj + dte * (a2q + bb2);
        const float sr_t = qsum(ahr + dte * amr) + dte * cr;
        const float sz_t = qsum(ahz + dte * amz) + dte * cz;
        const float hn_t = qsum(ahn + dte * amn) + dte * cn;

        const float r = sigmoid_f(sr_t + grf + brz_r);
        const float z = sigmoid_f(sz_t + gzf + brz_z);
        const float n = tanh_f(gnf + bin_n + r * (hn_t + bhn_n));
        const float hnew = m ? ((1.0f - z) * n + z * hode) : hode;

        if (q == 0) sh_h[nxt][j] = (_Float16)hnew;
        hj = hnew;
        if (m) hlast = hnew;
        seen |= m;
        xc0 = xn0; xc1 = xn1; xc2 = xn2; xc3 = xn3;
        dtc = dt_n; mc = m_n;
        WAVEBAR();
    }

    if (q == 0) sh_eo[j] = hlast;
    __syncthreads();
    float ao = 0.0f;
#pragma unroll
    for (int i = 0; i < 8; ++i) {
        const int c = kb + (((i + 2 * q) & 7) << 2);
        const float4 wv = *(const float4*)(W_out + (size_t)j * NH + c);
        const float4 hv = *(const float4*)(sh_eo + c);
        ao += wv.x * hv.x + wv.y * hv.y + wv.z * hv.z + wv.w * hv.w;
    }
    ao = qsum(ao);
    if (q == 0) out[(size_t)b * NH + j] = ao + b_out[j];
}

extern "C" void kernel_launch(void* const* d_in, const int* in_sizes, int n_in,
                              void* d_out, int out_size, void* d_ws, size_t ws_size,
                              hipStream_t stream) {
    const float* x     = (const float*)d_in[0];
    const float* tps   = (const float*)d_in[1];
    const int*   mask  = (const int*)  d_in[2];
    const float* W_ih  = (const float*)d_in[3];
    const float* W_hh  = (const float*)d_in[4];
    const float* b_ih  = (const float*)d_in[5];
    const float* b_hh  = (const float*)d_in[6];
    const float* nW1   = (const float*)d_in[7];
    const float* nb1   = (const float*)d_in[8];
    const float* nW2   = (const float*)d_in[9];
    const float* nb2   = (const float*)d_in[10];
    const float* W_out = (const float*)d_in[11];
    const float* b_out = (const float*)d_in[12];
    float* out = (float*)d_out;

    const size_t M_BYTES  = (size_t)384 * NH * sizeof(float);        // 196,608
    const size_t CV_OFF   = M_BYTES;                                  // cv: 1,536 B
    const size_t GI_OFF   = M_BYTES + 4096;
    const size_t GI_BYTES = (size_t)NT * NB * 384 * sizeof(ushort);  // 196,608,000
    float*  Mw  = (float*)d_ws;
    float*  cvp = (float*)((char*)d_ws + CV_OFF);
    ushort* giu = (ushort*)((char*)d_ws + GI_OFF);

    mfuse<<<dim3(384), dim3(128), 0, stream>>>(W_hh, nW2, Mw);
    if (ws_size >= GI_OFF + GI_BYTES) {
        cvk<<<dim3(3), dim3(128), 0, stream>>>(W_hh, nb2, cvp);
        gi_pre<<<dim3(NB, 8), dim3(384), 0, stream>>>(x, W_ih, giu);
        gruode_scan_mfma<<<dim3(NB), dim3(512), 0, stream>>>(
            tps, mask, W_hh, b_ih, b_hh, nW1, nb1, nW2, nb2,
            W_out, b_out, Mw, cvp, giu, out);
    } else {
        gruode_scan_valu<<<dim3(NB), dim3(512), 0, stream>>>(
            x, tps, mask, W_ih, W_hh, b_ih, b_hh,
            nW1, nb1, nW2, nb2, W_out, b_out, Mw, out);
    }
}